// Round 4
// baseline (142.146 us; speedup 1.0000x reference)
//
#include <hip/hip_runtime.h>

// ReconstructPatchImage: out[b,c,y,x] = sum of 8 permuted gathers of [B,HW,C] inputs.
// B=64, HW=196 (H=W=14), C=1024, all float32.
//
// Per-input flat (per-batch) source index for output (c, q=y*14+x):
//   in0 (l2r):  q*1024 + c
//   in1 (r2l):  (195-q)*1024 + c
//   in2 (t2b):  x*14336 + c*14 + y              (channel-mixing col-major view)
//   in3 (b2t):  (195 - x*14 - hi)*1024 + lo,  t=c*14+y, hi=t>>10, lo=t&1023
//   in4..in7: diag LUTs p5/p6/p7 (row perm of in0 pattern)
//
// R3: persistent pipeline. Grid = 256 blocks (1/CU); each block runs 4 batches
// x 8 inputs = 32 slabs through a 3-buffer global_load_lds pipeline with
// counted vmcnt (never 0 mid-loop). Per-batch output flush transposes through
// the just-consumed buffer (XOR swizzle, exactly SLAB floats) and issues
// dwordx4 stores; the next batch's slab loads remain in flight the whole time,
// so no tail is exposed until the very end.

#define N_HW 196
#define N_C  1024
#define SLAB 12544          // floats per 196x64 slab

struct Luts { unsigned short p5[196], p6[196], p7[196]; };

constexpr Luts make_luts() {
    Luts L{};
    int k = 0;
    for (int s = 0; s < 27; ++s) {
        int y0 = (s - 13 > 0) ? s - 13 : 0;
        int y1 = (s < 13) ? s : 13;
        for (int y = y0; y <= y1; ++y) {
            int x = s - y;
            L.p5[y * 14 + x] = (unsigned short)k;
            L.p7[y * 14 + (13 - x)] = (unsigned short)k;
            ++k;
        }
    }
    int k2 = 0;
    for (int s = 0; s < 27; ++s) {
        int x1 = (s < 13) ? s : 13;
        int x0 = (s - 13 > 0) ? s - 13 : 0;
        for (int x = x1; x >= x0; --x) {
            int y = s - x;
            L.p6[y * 14 + x] = (unsigned short)(195 - k2);
            ++k2;
        }
    }
    return L;
}

__constant__ Luts d_luts = make_luts();

__device__ __forceinline__ void gll16(const float* g, float* l) {
    __builtin_amdgcn_global_load_lds(
        (const __attribute__((address_space(1))) unsigned int*)g,
        (__attribute__((address_space(3))) unsigned int*)l,
        16, 0, 0);
}

#define BAR()   __builtin_amdgcn_s_barrier()
#define VMW(n)  asm volatile("s_waitcnt vmcnt(" #n ")" ::: "memory")
#define LGKM0   asm volatile("s_waitcnt lgkmcnt(0)" ::: "memory")

__global__ __launch_bounds__(448) void recon_kernel(
    const float* __restrict__ in0, const float* __restrict__ in1,
    const float* __restrict__ in2, const float* __restrict__ in3,
    const float* __restrict__ in4, const float* __restrict__ in5,
    const float* __restrict__ in6, const float* __restrict__ in7,
    float* __restrict__ out)
{
    __shared__ __align__(16) float lds[3 * SLAB];   // 150,528 B -> 1 block/CU
    const int tid  = threadIdx.x;
    const int lane = tid & 63;
    const int wv   = tid >> 6;
    const int w0   = __builtin_amdgcn_readfirstlane(wv);   // scalar wave id 0..6
    const int c0   = blockIdx.x * 64;                       // channel tile base
    const int b0   = blockIdx.y * 4;                        // first of 4 batches

    const float* ins[8] = { in0, in1, in2, in3, in4, in5, in6, in7 };
    float acc[28];

    // ---- stage slab s (input s&7, batch b0+(s>>3)) into buffer s%3 ----
    auto stage = [&](int s) {
        const int ii = s & 7;
        const int jj = s >> 3;
        const float* gb = ins[ii] + (size_t)(b0 + jj) * (N_HW * N_C);
        float* sb = lds + (s % 3) * SLAB;
        if (ii == 2) {                       // col-major forward
            #pragma unroll
            for (int j = 0; j < 7; ++j) {
                int ch = w0 + 7 * j;
                int i  = ch * 64 + lane;
                int x  = i / 224;
                int r  = i - x * 224;
                gll16(gb + x * 14336 + c0 * 14 + r * 4, sb + ch * 256);
            }
        } else if (ii == 3) {                // col-major reversed
            #pragma unroll
            for (int j = 0; j < 7; ++j) {
                int ch = w0 + 7 * j;
                int i  = ch * 64 + lane;
                int x  = i / 224;
                int jj4 = (i - x * 224) << 2;
                int t  = c0 * 14 + jj4;      // 16B group never straddles t%1024
                int hi = t >> 10, lo = t & 1023;
                int p  = 195 - x * 14 - hi;
                gll16(gb + p * N_C + lo, sb + ch * 256);
            }
        } else {                             // row-permuted (identity perm on load)
            #pragma unroll
            for (int j = 0; j < 7; ++j) {
                int ch = w0 + 7 * j;
                int i  = ch * 64 + lane;
                int p  = i >> 4;
                int rf = (i & 15) << 2;
                gll16(gb + p * N_C + c0 + rf, sb + ch * 256);
            }
        }
    };

    // ---- accumulate slab s from buffer s%3 ----
    auto do_acc = [&](int s) {
        const int ii = s & 7;
        const float* sb = lds + (s % 3) * SLAB;
        if (ii == 2 || ii == 3) {
            #pragma unroll
            for (int x = 0; x < 14; ++x) {
                float2 v = *(const float2*)(sb + x * 896 + lane * 14 + 2 * w0);
                acc[x]      += v.x;
                acc[14 + x] += v.y;
            }
        } else {
            #pragma unroll
            for (int k = 0; k < 28; ++k) {
                int q = w0 * 28 + k;
                int p;
                switch (ii) {
                    case 0: p = q;                          break;
                    case 1: p = 195 - q;                    break;
                    case 4: p = (int)d_luts.p5[q];          break;
                    case 5: p = (int)d_luts.p6[q];          break;
                    case 6: p = (int)d_luts.p7[q];          break;
                    default: p = (int)d_luts.p7[195 - q];   break;
                }
                float v = sb[p * 64 + lane];
                if (ii == 0) acc[k] = v; else acc[k] += v;
            }
        }
    };

    // ---- flush batch jj: swizzled transpose through buffer (8jj+7)%3, dwordx4 stores ----
    auto flush = [&](int jj) {
        float* tb = lds + ((8 * jj + 7) % 3) * SLAB;       // just consumed by do_acc
        #pragma unroll
        for (int k = 0; k < 28; ++k) {
            int q = w0 * 28 + k;
            tb[q * 64 + (lane ^ ((q >> 2) & 31))] = acc[k];
        }
        LGKM0; BAR();
        float* ob = out + (size_t)(b0 + jj) * (N_HW * N_C) + (size_t)c0 * N_HW;
        #pragma unroll
        for (int it = 0; it < 7; ++it) {
            int idx = tid + it * 448;                      // 0..3135
            int cg  = idx / 49;
            int g   = idx - cg * 49;                       // q-group: q = 4g..4g+3
            int swz = cg ^ (g & 31);
            float4 v;
            v.x = tb[(4 * g + 0) * 64 + swz];
            v.y = tb[(4 * g + 1) * 64 + swz];
            v.z = tb[(4 * g + 2) * 64 + swz];
            v.w = tb[(4 * g + 3) * 64 + swz];
            *(float4*)(ob + cg * N_HW + 4 * g) = v;
        }
        BAR();                                             // tb reads done before re-stage
    };

    // ---- phase: wait slab S, acc, (flush), prefetch S+3 ----
    #define PHASE(S, VMN)                                  \
        VMW(VMN); BAR();                                   \
        do_acc(S);                                         \
        LGKM0; BAR();                                      \
        if ((S & 7) == 7) flush(S >> 3);                   \
        if ((S) + 3 < 32) stage((S) + 3);

    stage(0); stage(1); stage(2);

    // vmcnt FIFO per wave: stage = 7 loads, flush = 7 stores.
    PHASE( 0, 14) PHASE( 1, 14) PHASE( 2, 14) PHASE( 3, 14)
    PHASE( 4, 14) PHASE( 5, 14) PHASE( 6, 14) PHASE( 7, 14)
    PHASE( 8, 21) PHASE( 9, 21) PHASE(10, 14) PHASE(11, 14)
    PHASE(12, 14) PHASE(13, 14) PHASE(14, 14) PHASE(15, 14)
    PHASE(16, 21) PHASE(17, 21) PHASE(18, 14) PHASE(19, 14)
    PHASE(20, 14) PHASE(21, 14) PHASE(22, 14) PHASE(23, 14)
    PHASE(24, 21) PHASE(25, 21) PHASE(26, 14) PHASE(27, 14)
    PHASE(28, 14) PHASE(29, 14) PHASE(30,  7) PHASE(31,  0)

    #undef PHASE
}

extern "C" void kernel_launch(void* const* d_in, const int* in_sizes, int n_in,
                              void* d_out, int out_size, void* d_ws, size_t ws_size,
                              hipStream_t stream) {
    dim3 grid(16, 16);   // x: channel tile (1024/64), y: batch quad (64/4)
    dim3 block(448);     // 7 waves; wave w owns q = w*28 .. w*28+27
    recon_kernel<<<grid, block, 0, stream>>>(
        (const float*)d_in[0], (const float*)d_in[1], (const float*)d_in[2],
        (const float*)d_in[3], (const float*)d_in[4], (const float*)d_in[5],
        (const float*)d_in[6], (const float*)d_in[7], (float*)d_out);
}